// Round 1
// baseline (1042.134 us; speedup 1.0000x reference)
//
#include <hip/hip_runtime.h>
#include <math.h>

#define BB 64
#define HH 1024
#define LL 2048
#define NVOC 32000
#define G3 3072

#define AST 68
#define WST 36

// ---------------- generic 64x32 C-tile GEMM: out[b,n] = sum_k A[b,k]*W[n,k] ----------------
// A: 64 rows (optional gather via ridx), W: row-major (N,K). Writes raw partial (no bias).
template<int NITER>
__device__ __forceinline__ void gemm32_dev(
    const float* __restrict__ Abase, const int* __restrict__ ridx,
    const float* __restrict__ W, int K, int k0, int n0,
    float* __restrict__ outBase, int ostride, float* lds)
{
    float* AsT = lds;                    // [2][16*AST]
    float* WsT = lds + 2 * 16 * AST;     // [2][16*WST]
    const int t = threadIdx.x;
    const int brow = t >> 2;             // 0..63
    const int kkA  = (t & 3) * 4;
    const float* arow = Abase + (size_t)(ridx ? ridx[brow] : brow) * K;
    const int wn  = t >> 3;              // 0..31
    const int kkW = (t & 7) * 2;
    const float* wrow = W + (size_t)(n0 + wn) * K;

    float4 aReg = *(const float4*)(arow + k0 + kkA);
    float2 wReg = *(const float2*)(wrow + k0 + kkW);

    float acc[4][2] = {};
    const int b4 = (t >> 4) * 4;         // 0..60
    const int n2 = (t & 15) * 2;         // 0..30
    int kc = k0;
    for (int it = 0; it < NITER; ++it) {
        float* As = AsT + (it & 1) * (16 * AST);
        float* Ws = WsT + (it & 1) * (16 * WST);
        As[(kkA + 0) * AST + brow] = aReg.x;
        As[(kkA + 1) * AST + brow] = aReg.y;
        As[(kkA + 2) * AST + brow] = aReg.z;
        As[(kkA + 3) * AST + brow] = aReg.w;
        Ws[(kkW + 0) * WST + wn] = wReg.x;
        Ws[(kkW + 1) * WST + wn] = wReg.y;
        __syncthreads();
        if (it + 1 < NITER) {
            kc += 16;
            aReg = *(const float4*)(arow + kc + kkA);
            wReg = *(const float2*)(wrow + kc + kkW);
        }
#pragma unroll
        for (int kk = 0; kk < 16; ++kk) {
            float4 a = *(const float4*)(As + kk * AST + b4);
            float2 w = *(const float2*)(Ws + kk * WST + n2);
            acc[0][0] += a.x * w.x; acc[0][1] += a.x * w.y;
            acc[1][0] += a.y * w.x; acc[1][1] += a.y * w.y;
            acc[2][0] += a.z * w.x; acc[2][1] += a.z * w.y;
            acc[3][0] += a.w * w.x; acc[3][1] += a.w * w.y;
        }
    }
#pragma unroll
    for (int i = 0; i < 4; ++i) {
        *(float2*)(outBase + (size_t)(b4 + i) * ostride + n0 + n2) =
            make_float2(acc[i][0], acc[i][1]);
    }
}

// gate GEMMs: z=0 gi0 (embed gather @ Wih0), z=1 gh0, z=2 gh1, z=3 gi1 (h0 @ Wih1)
__global__ __launch_bounds__(256) void gates_kernel(
    const float* __restrict__ emb, const int* __restrict__ idx,
    const float* __restrict__ lasth, const float* __restrict__ h0,
    const float* __restrict__ Wih0, const float* __restrict__ Whh0,
    const float* __restrict__ Whh1, const float* __restrict__ Wih1,
    float* __restrict__ parts, int zbase)
{
    __shared__ float lds[2 * 16 * AST + 2 * 16 * WST];
    const int z = zbase + blockIdx.z;
    const float* Ab; const int* ridx = nullptr; const float* W;
    switch (z) {
        case 0:  Ab = emb;             ridx = idx; W = Wih0; break;
        case 1:  Ab = lasth;                       W = Whh0; break;
        case 2:  Ab = lasth + BB * HH;             W = Whh1; break;
        default: Ab = h0;                          W = Wih1; break;
    }
    const int ks = blockIdx.y;
    const int n0 = blockIdx.x * 32;
    float* outBase = parts + (size_t)(z * 2 + ks) * BB * G3;
    gemm32_dev<32>(Ab, ridx, W, 1024, ks * 512, n0, outBase, G3, lds);
}

__global__ __launch_bounds__(256) void gru_combine_kernel(
    const float* __restrict__ parts, const float* __restrict__ b_ih,
    const float* __restrict__ b_hh, const float* __restrict__ hprev,
    float* __restrict__ hout, int zi, int zh)
{
    const int id = blockIdx.x * 256 + threadIdx.x;   // 0..65535
    const int b = id >> 10, j = id & 1023;
    const float* pi0 = parts + ((size_t)(zi * 2 + 0) * BB + b) * G3;
    const float* pi1 = parts + ((size_t)(zi * 2 + 1) * BB + b) * G3;
    const float* ph0 = parts + ((size_t)(zh * 2 + 0) * BB + b) * G3;
    const float* ph1 = parts + ((size_t)(zh * 2 + 1) * BB + b) * G3;
    float ir = pi0[j]        + pi1[j]        + b_ih[j];
    float iz = pi0[j + 1024] + pi1[j + 1024] + b_ih[j + 1024];
    float in_= pi0[j + 2048] + pi1[j + 2048] + b_ih[j + 2048];
    float hr = ph0[j]        + ph1[j]        + b_hh[j];
    float hz = ph0[j + 1024] + ph1[j + 1024] + b_hh[j + 1024];
    float hn = ph0[j + 2048] + ph1[j + 2048] + b_hh[j + 2048];
    float r = 1.f / (1.f + __expf(-(ir + hr)));
    float z = 1.f / (1.f + __expf(-(iz + hz)));
    float n = tanhf(in_ + r * hn);
    hout[id] = (1.f - z) * n + z * hprev[(size_t)b * HH + j];
}

// flash-style attention chunk: scores + online softmax + partial context, enc read ONCE
__global__ __launch_bounds__(256) void attn_chunk_kernel(
    const float* __restrict__ enc, const float* __restrict__ h1,
    float* __restrict__ scores, float* __restrict__ mpart,
    float* __restrict__ spart, float* __restrict__ ctxpart)
{
    __shared__ float enc_s[8][1024];
    __shared__ float h1_s[1024];
    __shared__ float sc_s[8];
    const int t = threadIdx.x;
    const int c = blockIdx.x;   // chunk 0..15
    const int b = blockIdx.y;   // 0..63
    const int l0 = c * 128;
    *(float4*)(h1_s + t * 4) = *(const float4*)(h1 + (size_t)b * HH + t * 4);
    const size_t encBase = (size_t)b * LL * HH;
    float m_run = -INFINITY, s_run = 0.f;
    float4 ctx = {0.f, 0.f, 0.f, 0.f};
    float4 pf[8];
#pragma unroll
    for (int r = 0; r < 8; ++r)
        pf[r] = *(const float4*)(enc + encBase + (size_t)(l0 + r) * HH + t * 4);
    const int w = t >> 6, lane = t & 63;

    for (int it = 0; it < 16; ++it) {
        __syncthreads();  // protect enc_s/sc_s from previous iteration readers
#pragma unroll
        for (int r = 0; r < 8; ++r)
            *(float4*)(&enc_s[r][t * 4]) = pf[r];
        __syncthreads();
        if (it + 1 < 16) {
#pragma unroll
            for (int r = 0; r < 8; ++r)
                pf[r] = *(const float4*)(enc + encBase +
                        (size_t)(l0 + (it + 1) * 8 + r) * HH + t * 4);
        }
        // scores for 8 staged rows; wave-strided LDS addressing (lane*4 + j*256)
        for (int r = w; r < 8; r += 4) {
            float acc = 0.f;
#pragma unroll
            for (int j = 0; j < 4; ++j) {
                float4 ev = *(const float4*)(&enc_s[r][lane * 4 + j * 256]);
                float4 hv = *(const float4*)(&h1_s[lane * 4 + j * 256]);
                acc += ev.x * hv.x + ev.y * hv.y + ev.z * hv.z + ev.w * hv.w;
            }
#pragma unroll
            for (int off = 32; off > 0; off >>= 1) acc += __shfl_down(acc, off, 64);
            if (lane == 0) {
                sc_s[r] = acc;
                scores[(size_t)b * LL + l0 + it * 8 + r] = acc;
            }
        }
        __syncthreads();
        float m_new = m_run;
#pragma unroll
        for (int r = 0; r < 8; ++r) m_new = fmaxf(m_new, sc_s[r]);
        float alpha = __expf(m_run - m_new);
        s_run *= alpha;
        ctx.x *= alpha; ctx.y *= alpha; ctx.z *= alpha; ctx.w *= alpha;
#pragma unroll
        for (int r = 0; r < 8; ++r) {
            float p = __expf(sc_s[r] - m_new);
            s_run += p;
            float4 ev = *(const float4*)(&enc_s[r][t * 4]);
            ctx.x += p * ev.x; ctx.y += p * ev.y; ctx.z += p * ev.z; ctx.w += p * ev.w;
        }
        m_run = m_new;
    }
    *(float4*)(ctxpart + ((size_t)b * 16 + c) * HH + t * 4) = ctx;
    if (t == 0) { mpart[b * 16 + c] = m_run; spart[b * 16 + c] = s_run; }
}

__global__ __launch_bounds__(256) void attn_combine_kernel(
    const float* __restrict__ scores, const float* __restrict__ mpart,
    const float* __restrict__ spart, const float* __restrict__ ctxpart,
    const float* __restrict__ h1, float* __restrict__ concat,
    float* __restrict__ attn_out)
{
    const int b = blockIdx.x, t = threadIdx.x;
    float M = -INFINITY;
#pragma unroll
    for (int c = 0; c < 16; ++c) M = fmaxf(M, mpart[b * 16 + c]);
    float e[16];
    float S = 0.f;
#pragma unroll
    for (int c = 0; c < 16; ++c) {
        e[c] = __expf(mpart[b * 16 + c] - M);
        S += spart[b * 16 + c] * e[c];
    }
    const float inv = 1.f / S;
    float4 acc = {0.f, 0.f, 0.f, 0.f};
#pragma unroll
    for (int c = 0; c < 16; ++c) {
        float4 v = *(const float4*)(ctxpart + ((size_t)b * 16 + c) * HH + t * 4);
        acc.x += e[c] * v.x; acc.y += e[c] * v.y;
        acc.z += e[c] * v.z; acc.w += e[c] * v.w;
    }
    acc.x *= inv; acc.y *= inv; acc.z *= inv; acc.w *= inv;
    *(float4*)(concat + (size_t)b * 2048 + 1024 + t * 4) = acc;
    *(float4*)(concat + (size_t)b * 2048 + t * 4) =
        *(const float4*)(h1 + (size_t)b * HH + t * 4);
#pragma unroll
    for (int i = 0; i < 8; ++i) {
        int l = t + 256 * i;
        attn_out[(size_t)b * LL + l] = __expf(scores[(size_t)b * LL + l] - M) * inv;
    }
}

__global__ __launch_bounds__(256) void wc_kernel(
    const float* __restrict__ concat, const float* __restrict__ Wc,
    float* __restrict__ wcpart)
{
    __shared__ float lds[2 * 16 * AST + 2 * 16 * WST];
    const int ks = blockIdx.y;
    const int n0 = blockIdx.x * 32;
    gemm32_dev<16>(concat, nullptr, Wc, 2048, ks * 256, n0,
                   wcpart + (size_t)ks * (BB * HH), HH, lds);
}

__global__ __launch_bounds__(256) void co_combine_kernel(
    const float* __restrict__ wcpart, const float* __restrict__ bc,
    float* __restrict__ co)
{
    const int id = blockIdx.x * 256 + threadIdx.x;   // 0..65535
    const int j = id & 1023;
    float s = bc[j];
#pragma unroll
    for (int ks = 0; ks < 8; ++ks) s += wcpart[(size_t)ks * (BB * HH) + id];
    co[id] = tanhf(s);
}

// 64x64 C-tile GEMM for logits: out[b,v] = sum_k co[b,k]*Wout[v,k] + bout[v]
__global__ __launch_bounds__(256) void wout_kernel(
    const float* __restrict__ co, const float* __restrict__ Wo,
    const float* __restrict__ bout, float* __restrict__ out)
{
    __shared__ float AsT[2 * 16 * 68];
    __shared__ float WsT[2 * 16 * 68];
    const int t = threadIdx.x;
    const int n0 = blockIdx.x * 64;
    const int brow = t >> 2;
    const int kk4 = (t & 3) * 4;
    const float* arow = co + (size_t)brow * 1024;
    const float* wrow = Wo + (size_t)(n0 + brow) * 1024;
    float4 aReg = *(const float4*)(arow + kk4);
    float4 wReg = *(const float4*)(wrow + kk4);
    float acc[4][4] = {};
    const int b4 = (t >> 4) * 4;
    const int n4 = (t & 15) * 4;
    int kc = 0;
    for (int it = 0; it < 64; ++it) {
        float* As = AsT + (it & 1) * (16 * 68);
        float* Ws = WsT + (it & 1) * (16 * 68);
        As[(kk4 + 0) * 68 + brow] = aReg.x;
        As[(kk4 + 1) * 68 + brow] = aReg.y;
        As[(kk4 + 2) * 68 + brow] = aReg.z;
        As[(kk4 + 3) * 68 + brow] = aReg.w;
        Ws[(kk4 + 0) * 68 + brow] = wReg.x;
        Ws[(kk4 + 1) * 68 + brow] = wReg.y;
        Ws[(kk4 + 2) * 68 + brow] = wReg.z;
        Ws[(kk4 + 3) * 68 + brow] = wReg.w;
        __syncthreads();
        if (it + 1 < 64) {
            kc += 16;
            aReg = *(const float4*)(arow + kc + kk4);
            wReg = *(const float4*)(wrow + kc + kk4);
        }
#pragma unroll
        for (int kk = 0; kk < 16; ++kk) {
            float4 a = *(const float4*)(As + kk * 68 + b4);
            float4 w = *(const float4*)(Ws + kk * 68 + n4);
            acc[0][0] += a.x * w.x; acc[0][1] += a.x * w.y; acc[0][2] += a.x * w.z; acc[0][3] += a.x * w.w;
            acc[1][0] += a.y * w.x; acc[1][1] += a.y * w.y; acc[1][2] += a.y * w.z; acc[1][3] += a.y * w.w;
            acc[2][0] += a.z * w.x; acc[2][1] += a.z * w.y; acc[2][2] += a.z * w.z; acc[2][3] += a.z * w.w;
            acc[3][0] += a.w * w.x; acc[3][1] += a.w * w.y; acc[3][2] += a.w * w.z; acc[3][3] += a.w * w.w;
        }
    }
    const float4 bv = *(const float4*)(bout + n0 + n4);
#pragma unroll
    for (int i = 0; i < 4; ++i) {
        float4 v = make_float4(acc[i][0] + bv.x, acc[i][1] + bv.y,
                               acc[i][2] + bv.z, acc[i][3] + bv.w);
        *(float4*)(out + (size_t)(b4 + i) * NVOC + n0 + n4) = v;
    }
}

extern "C" void kernel_launch(void* const* d_in, const int* in_sizes, int n_in,
                              void* d_out, int out_size, void* d_ws, size_t ws_size,
                              hipStream_t stream)
{
    const int*   idx   = (const int*)d_in[0];
    const float* lasth = (const float*)d_in[1];
    const float* enc   = (const float*)d_in[2];
    const float* emb   = (const float*)d_in[3];
    const float* Wih0  = (const float*)d_in[4];
    const float* Whh0  = (const float*)d_in[5];
    const float* bih0  = (const float*)d_in[6];
    const float* bhh0  = (const float*)d_in[7];
    const float* Wih1  = (const float*)d_in[8];
    const float* Whh1  = (const float*)d_in[9];
    const float* bih1  = (const float*)d_in[10];
    const float* bhh1  = (const float*)d_in[11];
    const float* Wc    = (const float*)d_in[12];
    const float* bc    = (const float*)d_in[13];
    const float* Wout  = (const float*)d_in[14];
    const float* bout  = (const float*)d_in[15];
    float* out = (float*)d_out;
    float* ws  = (float*)d_ws;

    // ws layout (floats)
    float* parts   = ws;                 // 4*2*64*3072 = 1,572,864
    float* scores  = ws + 1572864;       // 131,072
    float* mpart   = ws + 1703936;       // 1,024
    float* spart   = ws + 1704960;       // 1,024
    float* ctxpart = ws + 1705984;       // 1,048,576
    float* concat  = ws + 2754560;       // 131,072
    float* wcpart  = ws + 2885632;       // 524,288
    float* co      = ws + 3409920;       // 65,536   (total 3,475,456 floats = 13.9 MB)

    float* outLogits = out;                       // 64*32000
    float* hid0 = out + 2048000;                  // 64*1024
    float* hid1 = out + 2048000 + 65536;          // 64*1024
    float* attnOut = out + 2179072;               // 64*2048

    // layer-0 gates (gi0, gh0) + layer-1 recurrent gates (gh1)
    gates_kernel<<<dim3(96, 2, 3), 256, 0, stream>>>(emb, idx, lasth, hid0,
        Wih0, Whh0, Whh1, Wih1, parts, 0);
    gru_combine_kernel<<<256, 256, 0, stream>>>(parts, bih0, bhh0, lasth, hid0, 0, 1);
    // layer-1 input gates gi1 = h0 @ Wih1^T
    gates_kernel<<<dim3(96, 2, 1), 256, 0, stream>>>(emb, idx, lasth, hid0,
        Wih0, Whh0, Whh1, Wih1, parts, 3);
    gru_combine_kernel<<<256, 256, 0, stream>>>(parts, bih1, bhh1, lasth + BB * HH,
        hid1, 3, 2);
    // fused attention: scores + online softmax + partial context (enc read once)
    attn_chunk_kernel<<<dim3(16, 64), 256, 0, stream>>>(enc, hid1, scores,
        mpart, spart, ctxpart);
    attn_combine_kernel<<<64, 256, 0, stream>>>(scores, mpart, spart, ctxpart,
        hid1, concat, attnOut);
    // concat @ Wc^T, tanh
    wc_kernel<<<dim3(32, 8), 256, 0, stream>>>(concat, Wc, wcpart);
    co_combine_kernel<<<256, 256, 0, stream>>>(wcpart, bc, co);
    // logits
    wout_kernel<<<500, 256, 0, stream>>>(co, Wout, bout, outLogits);
}